// Round 3
// baseline (984.104 us; speedup 1.0000x reference)
//
#include <hip/hip_runtime.h>
#include <hip/hip_bf16.h>

typedef unsigned short u16;
typedef unsigned int u32;
typedef __attribute__((ext_vector_type(8))) short short8;
typedef __attribute__((ext_vector_type(4))) float f32x4;

#define Bq 8
#define Cc 128
#define C4 512
#define Hh 256
#define Wf 256
#define H2 128
#define W2 128
#define HW2 16384

__device__ __forceinline__ float gelu_f(float x) {
    return 0.5f * x * (1.0f + erff(x * 0.70710678118654752f));
}
__device__ __forceinline__ float bf2f(u16 u) {
    union { float f; u32 i; } v; v.i = ((u32)u) << 16; return v.f;
}
__device__ __forceinline__ u16 f2bf(float f) {
    union { float f; u32 i; } v; v.f = f;
    u32 r = v.i + 0x7FFFu + ((v.i >> 16) & 1u);
    return (u16)(r >> 16);
}

// ---------------- weights f32 -> bf16 (pw1 pre-scaled by gn_g) ----------------
__global__ __launch_bounds__(256) void k_wconv(const float* __restrict__ w_c1,
                                               const float* __restrict__ pw1,
                                               const float* __restrict__ pw2,
                                               const float* __restrict__ w_c2,
                                               const float* __restrict__ gn_g,
                                               u16* __restrict__ wb) {
    int i = blockIdx.x * 256 + threadIdx.x;   // 0..163839
    float v;
    if (i < 65536) v = w_c1[i];
    else if (i < 81920) v = pw1[i - 65536] * gn_g[(i - 65536) & 127];
    else if (i < 98304) v = pw2[i - 81920];
    else v = w_c2[i - 98304];
    wb[i] = f2bf(v);
}

// ---------------- LN-fold vectors: wgs[o]=sum_c w*g, wbv[o]=sum_c w*b --------
__global__ __launch_bounds__(128) void k_wvec(const float* __restrict__ pw1,
                                              const float* __restrict__ gg,
                                              const float* __restrict__ gb,
                                              float* __restrict__ wbv,
                                              float* __restrict__ wgs) {
    int o = threadIdx.x;
    float a = 0.f, bv = 0.f;
    for (int c = 0; c < 128; ++c) {
        float w = pw1[o * 128 + c];
        a += w * gg[c];
        bv += w * gb[c];
    }
    wgs[o] = a;
    wbv[o] = bv;
}

// ---------------- DWT: x NCHW f32 -> h1 pixel-major bf16 [b][pix][512] --------
__global__ __launch_bounds__(256) void k_dwt(const float* __restrict__ x,
                                             u16* __restrict__ h1) {
    __shared__ float lin[2 * 4224];
    __shared__ __align__(16) u16 obuf[16 * 512];
    const int t = threadIdx.x;
    const int b = blockIdx.z, oi = blockIdx.y, jt = blockIdx.x;
    {
        int c = t & 127, h = t >> 7;
        const float* xp = x + (((long)(b * Cc + c)) * Hh + (2 * oi + h)) * Wf + jt * 32;
        float* lp = lin + h * 4224 + c * 33;
#pragma unroll
        for (int q = 0; q < 8; ++q) {
            float4 v = *(const float4*)(xp + q * 4);
            lp[q * 4 + 0] = v.x; lp[q * 4 + 1] = v.y;
            lp[q * 4 + 2] = v.z; lp[q * 4 + 3] = v.w;
        }
    }
    __syncthreads();
    {
        int c = t & 127, pg = t >> 7;
        const float* l0 = lin + c * 33;
        const float* l1 = lin + 4224 + c * 33;
#pragma unroll
        for (int u = 0; u < 8; ++u) {
            int p = pg * 8 + u;
            float x00 = l0[2 * p], x01 = l0[2 * p + 1];
            float x10 = l1[2 * p], x11 = l1[2 * p + 1];
            obuf[p * 512 + 0 * 128 + c] = f2bf((x00 + x01 + x10 + x11) * 0.5f);
            obuf[p * 512 + 1 * 128 + c] = f2bf((x00 + x01 - x10 - x11) * 0.5f);
            obuf[p * 512 + 2 * 128 + c] = f2bf((x00 - x01 + x10 - x11) * 0.5f);
            obuf[p * 512 + 3 * 128 + c] = f2bf((x00 - x01 - x10 + x11) * 0.5f);
        }
    }
    __syncthreads();
    {
        int p = t >> 4, seg = t & 15;
        long opix = (long)b * HW2 + (long)oi * W2 + jt * 16 + p;
        const uint4* src = (const uint4*)(obuf + p * 512 + seg * 32);
        uint4* dst = (uint4*)(h1 + opix * 512 + seg * 32);
        dst[0] = src[0]; dst[1] = src[1]; dst[2] = src[2]; dst[3] = src[3];
    }
}

// ---------------- bf16 MFMA NT-GEMM with fused stats + coalesced epilogue -----
// C[M][N] = A[M][K] * B[N][K]^T.
// EPI: 0 raw bf16 store; 1 LN-folded affine + gelu (pw1); 2 +bias +residual (pw2)
// STATS: 0 none; 1 per-col sum/sq atomics (conv1); 2 per-row (conv2)
template <int EPI, int STATS>
__global__ __launch_bounds__(256) void k_mfma(const u16* __restrict__ A,
                                              const u16* __restrict__ Bw,
                                              u16* __restrict__ C,
                                              const float* __restrict__ bias,
                                              const u16* __restrict__ res,
                                              const float* __restrict__ wbv,
                                              const float* __restrict__ wgs,
                                              const float* __restrict__ lnS,
                                              const float* __restrict__ lnQ,
                                              float* __restrict__ statS,
                                              float* __restrict__ statQ,
                                              int N, int K,
                                              long aBs, long bBs, long cBs) {
    __shared__ __align__(16) u16 lds[16384];   // staging (2x8K), then C bounce
    __shared__ float sblk[128], qblk[128];
    const int t = threadIdx.x;
    const int lane = t & 63, w = t >> 6, wr = w >> 1, wc = w & 1;
    const int b = blockIdx.z;
    const int m0 = blockIdx.y * 128, n0 = blockIdx.x * 128;
    const u16* Ab = A + (long)b * aBs + (long)m0 * K;
    const u16* Bb = Bw + (long)b * bBs + (long)n0 * K;

    // preload per-col params / zero stats (visible after first __syncthreads)
    if (t < 128) {
        if (STATS) { sblk[t] = 0.f; qblk[t] = 0.f; }
        if (EPI == 1) {
            const float invN = 1.0f / 2097152.0f;
            float mu = lnS[b] * invN;
            float var = lnQ[b] * invN - mu * mu;
            float rs = rsqrtf(var + 1e-5f);
            sblk[t] = bias[t] + wbv[t] - mu * rs * wgs[t];
        }
        if (EPI == 2) sblk[t] = bias[t];
    }

    uint4 ra[4], rb[4];
#define GLOAD(dst, base, k0)                                                     \
    {                                                                            \
        _Pragma("unroll")                                                        \
        for (int i = 0; i < 4; ++i) {                                            \
            int s = i * 256 + t;                                                 \
            dst[i] = *(const uint4*)(base + (long)(s >> 3) * K + (k0) + (s & 7) * 8); \
        }                                                                        \
    }
#define LWRITE(ofs, src)                                                         \
    {                                                                            \
        _Pragma("unroll")                                                        \
        for (int i = 0; i < 4; ++i) {                                            \
            int s = i * 256 + t;                                                 \
            int row_ = s >> 3, ch_ = s & 7;                                      \
            *(uint4*)((char*)lds + (ofs) + row_ * 128 + 16 * (ch_ ^ (row_ & 7))) = src[i]; \
        }                                                                        \
    }

    f32x4 acc[4][4];
#pragma unroll
    for (int i = 0; i < 4; ++i)
#pragma unroll
        for (int j = 0; j < 4; ++j) acc[i][j] = (f32x4){0.f, 0.f, 0.f, 0.f};

    GLOAD(ra, Ab, 0)
    GLOAD(rb, Bb, 0)
    const int r15 = lane & 15, kq = lane >> 4;
    for (int k0 = 0; k0 < K; k0 += 64) {
        __syncthreads();
        LWRITE(0, ra)
        LWRITE(16384, rb)
        __syncthreads();
        if (k0 + 64 < K) { GLOAD(ra, Ab, k0 + 64) GLOAD(rb, Bb, k0 + 64) }
#pragma unroll
        for (int ks = 0; ks < 2; ++ks) {
            short8 af[4], bfv[4];
            const int ch = ks * 4 + kq;
#pragma unroll
            for (int mi = 0; mi < 4; ++mi) {
                int row = wr * 64 + mi * 16 + r15;
                af[mi] = *(const short8*)((const char*)lds + row * 128 + 16 * (ch ^ (row & 7)));
            }
#pragma unroll
            for (int ni = 0; ni < 4; ++ni) {
                int row = wc * 64 + ni * 16 + r15;
                bfv[ni] = *(const short8*)((const char*)lds + 16384 + row * 128 + 16 * (ch ^ (row & 7)));
            }
#pragma unroll
            for (int mi = 0; mi < 4; ++mi)
#pragma unroll
                for (int ni = 0; ni < 4; ++ni)
                    acc[mi][ni] = __builtin_amdgcn_mfma_f32_16x16x32_bf16(
                        af[mi], bfv[ni], acc[mi][ni], 0, 0, 0);
        }
    }
    __syncthreads();   // staging reads done; lds reusable as C bounce

    // --- bounce raw acc (bf16) into lds: [row][col ^ ((row&7)<<3)] ---
#pragma unroll
    for (int mi = 0; mi < 4; ++mi)
#pragma unroll
        for (int ni = 0; ni < 4; ++ni)
#pragma unroll
            for (int r = 0; r < 4; ++r) {
                int row = wr * 64 + mi * 16 + kq * 4 + r;
                int col = wc * 64 + ni * 16 + r15;
                lds[row * 128 + (col ^ ((row & 7) << 3))] = f2bf(acc[mi][ni][r]);
            }

    // --- fused stats from f32 acc ---
    if (STATS == 1) {   // per-col (cols = channels), reduce over rows
#pragma unroll
        for (int ni = 0; ni < 4; ++ni) {
            float s = 0.f, q2 = 0.f;
#pragma unroll
            for (int mi = 0; mi < 4; ++mi)
#pragma unroll
                for (int r = 0; r < 4; ++r) {
                    float v = acc[mi][ni][r];
                    s += v; q2 += v * v;
                }
            s += __shfl_down(s, 32); s += __shfl_down(s, 16);
            q2 += __shfl_down(q2, 32); q2 += __shfl_down(q2, 16);
            if (lane < 16) {
                int col = wc * 64 + ni * 16 + r15;
                atomicAdd(&sblk[col], s);
                atomicAdd(&qblk[col], q2);
            }
        }
    }
    if (STATS == 2) {   // per-row (rows = channels), reduce over cols
#pragma unroll
        for (int mi = 0; mi < 4; ++mi)
#pragma unroll
            for (int r = 0; r < 4; ++r) {
                float s = 0.f, q2 = 0.f;
#pragma unroll
                for (int ni = 0; ni < 4; ++ni) {
                    float v = acc[mi][ni][r];
                    s += v; q2 += v * v;
                }
                s += __shfl_down(s, 8); s += __shfl_down(s, 4);
                s += __shfl_down(s, 2); s += __shfl_down(s, 1);
                q2 += __shfl_down(q2, 8); q2 += __shfl_down(q2, 4);
                q2 += __shfl_down(q2, 2); q2 += __shfl_down(q2, 1);
                if (r15 == 0) {
                    int row = wr * 64 + mi * 16 + kq * 4 + r;
                    atomicAdd(&sblk[row], s);
                    atomicAdd(&qblk[row], q2);
                }
            }
    }
    __syncthreads();   // C tile + block stats complete

    // --- coalesced read-back + epilogue transform + uint4 stores ---
    u16* Cb = C + (long)b * cBs;
    {
        int row = t >> 1, half = (t & 1) * 64;
        int sx = (row & 7) << 3;
        long gbase = (long)(m0 + row) * N + n0;
        float rs = 1.f;
        if (EPI == 1) {
            const float invN = 1.0f / 2097152.0f;
            float mu = lnS[b] * invN;
            float var = lnQ[b] * invN - mu * mu;
            rs = rsqrtf(var + 1e-5f);
        }
#pragma unroll
        for (int q = 0; q < 8; ++q) {
            int c = half + q * 8;
            uint4 raw = *(const uint4*)(lds + row * 128 + (c ^ sx));
            if (EPI == 0) {
                *(uint4*)(Cb + gbase + c) = raw;
            } else {
                u16* pv = (u16*)&raw;
                uint4 rr;
                if (EPI == 2) rr = *(const uint4*)(res + (long)b * cBs + gbase + c);
                const u16* rv = (const u16*)&rr;
#pragma unroll
                for (int u = 0; u < 8; ++u) {
                    float v = bf2f(pv[u]);
                    if (EPI == 1) v = gelu_f(rs * v + sblk[c + u]);
                    if (EPI == 2) v = v + sblk[c + u] + bf2f(rv[u]);
                    pv[u] = f2bf(v);
                }
                *(uint4*)(Cb + gbase + c) = raw;
            }
        }
    }
    if (STATS && t < 128) {
        int base = (STATS == 1) ? n0 : m0;
        atomicAdd(statS + base + t, sblk[t]);
        atomicAdd(statQ + base + t, qblk[t]);
    }
#undef GLOAD
#undef LWRITE
}

// ---------------- BN1 apply + gelu: bufA -> bufH ----------------
__global__ __launch_bounds__(256) void k_bn1_gelu(const u16* __restrict__ in,
                                                  u16* __restrict__ out,
                                                  const float* __restrict__ sum,
                                                  const float* __restrict__ sq,
                                                  const float* __restrict__ g,
                                                  const float* __restrict__ bb) {
    long e = ((long)blockIdx.x * 256 + threadIdx.x) * 8;
    int c0 = (int)(e & 127);
    uint4 raw = *(const uint4*)(in + e);
    u16* pv = (u16*)&raw;
    const float invN = 1.0f / 131072.0f;
#pragma unroll
    for (int u = 0; u < 8; ++u) {
        int c = c0 + u;
        float mu = sum[c] * invN;
        float var = sq[c] * invN - mu * mu;
        float rscale = rsqrtf(var + 1e-5f);
        float sc = rscale * g[c], sh = bb[c] - mu * sc;
        pv[u] = f2bf(gelu_f(bf2f(pv[u]) * sc + sh));
    }
    *(uint4*)(out + e) = raw;
}

// ---------------- depthwise 3x3 NHWC bf16 + fused LN stats ----------------
__global__ __launch_bounds__(256) void k_dwconv(const u16* __restrict__ x,
                                                u16* __restrict__ y,
                                                const float* __restrict__ w,
                                                const float* __restrict__ bias,
                                                float* __restrict__ lnS,
                                                float* __restrict__ lnQ) {
    __shared__ float wl[1152];
    const int t = threadIdx.x;
    if (t < 144) {
        *(float4*)(wl + t * 8)     = *(const float4*)(w + t * 8);
        *(float4*)(wl + t * 8 + 4) = *(const float4*)(w + t * 8 + 4);
    }
    __syncthreads();
    const int cg = t & 15, jj = t >> 4;
    const int j = blockIdx.x * 16 + jj, i = blockIdx.y, b = blockIdx.z;
    const u16* xb = x + (long)b * HW2 * 128;
    float acc[8];
#pragma unroll
    for (int u = 0; u < 8; ++u) acc[u] = bias[cg * 8 + u];
#pragma unroll
    for (int di = -1; di <= 1; ++di) {
        int row = i + di;
        if (row < 0 || row >= H2) continue;
#pragma unroll
        for (int dj = -1; dj <= 1; ++dj) {
            int col = j + dj;
            if (col < 0 || col >= W2) continue;
            uint4 raw = *(const uint4*)(xb + ((long)row * W2 + col) * 128 + cg * 8);
            const u16* pv = (const u16*)&raw;
            int tap = (di + 1) * 3 + (dj + 1);
#pragma unroll
            for (int u = 0; u < 8; ++u)
                acc[u] = fmaf(bf2f(pv[u]), wl[(cg * 8 + u) * 9 + tap], acc[u]);
        }
    }
    uint4 out; u16* ov = (u16*)&out;
    float s = 0.f, q2 = 0.f;
#pragma unroll
    for (int u = 0; u < 8; ++u) {
        ov[u] = f2bf(acc[u]);
        s += acc[u]; q2 += acc[u] * acc[u];
    }
    *(uint4*)(y + ((long)b * HW2 + (long)i * W2 + j) * 128 + cg * 8) = out;
#pragma unroll
    for (int off = 32; off; off >>= 1) {
        s += __shfl_down(s, off);
        q2 += __shfl_down(q2, off);
    }
    __shared__ float r1[4], r2[4];
    if ((t & 63) == 0) { r1[t >> 6] = s; r2[t >> 6] = q2; }
    __syncthreads();
    if (t == 0) {
        atomicAdd(lnS + b, r1[0] + r1[1] + r1[2] + r1[3]);
        atomicAdd(lnQ + b, r2[0] + r2[1] + r2[2] + r2[3]);
    }
}

// ---------------- BN2 + GELU + IDWT: z channel-major bf16 -> out f32 NCHW -----
__global__ __launch_bounds__(256) void k_bn2_gelu_idwt(const u16* __restrict__ z,
                                                       float* __restrict__ out,
                                                       const float* __restrict__ sum,
                                                       const float* __restrict__ sq,
                                                       const float* __restrict__ g,
                                                       const float* __restrict__ bb) {
    int tid = blockIdx.x * 256 + threadIdx.x;
    int j2 = tid & 63;
    int i  = (tid >> 6) & 127;
    int c  = (tid >> 13) & 127;
    int b  = tid >> 20;
    const float invN = 1.0f / 131072.0f;
    long qs = (long)Cc * HW2;
    long base = (((long)b * C4 + c) * H2 + i) * W2 + 2 * j2;
    float sb[4][2];
#pragma unroll
    for (int q = 0; q < 4; ++q) {
        int ch = q * 128 + c;
        float mu = sum[ch] * invN;
        float var = sq[ch] * invN - mu * mu;
        float rscale = rsqrtf(var + 1e-5f);
        float sc = rscale * g[ch], sh = bb[ch] - mu * sc;
        u32 raw = *(const u32*)(z + base + (long)q * qs);
        sb[q][0] = gelu_f(bf2f((u16)(raw & 0xFFFFu)) * sc + sh);
        sb[q][1] = gelu_f(bf2f((u16)(raw >> 16)) * sc + sh);
    }
    float4 top, bot;
    float* tp = &top.x;
    float* bp = &bot.x;
#pragma unroll
    for (int px = 0; px < 2; ++px) {
        float ll = sb[0][px], lh = sb[1][px], hl = sb[2][px], hh = sb[3][px];
        tp[px * 2 + 0] = (ll + lh + hl + hh) * 0.5f;
        tp[px * 2 + 1] = (ll + lh - hl - hh) * 0.5f;
        bp[px * 2 + 0] = (ll - lh + hl - hh) * 0.5f;
        bp[px * 2 + 1] = (ll - lh - hl + hh) * 0.5f;
    }
    float* optr = out + ((long)(b * Cc + c) * Hh + 2 * i) * Wf + 4 * j2;
    *(float4*)optr = top;
    *(float4*)(optr + Wf) = bot;
}

extern "C" void kernel_launch(void* const* d_in, const int* in_sizes, int n_in,
                              void* d_out, int out_size, void* d_ws, size_t ws_size,
                              hipStream_t stream) {
    const float* x     = (const float*)d_in[0];
    const float* w_c1  = (const float*)d_in[1];
    const float* bn1_g = (const float*)d_in[3];
    const float* bn1_b = (const float*)d_in[4];
    const float* dw_w  = (const float*)d_in[5];
    const float* dw_b  = (const float*)d_in[6];
    const float* gn_g  = (const float*)d_in[7];
    const float* gn_b  = (const float*)d_in[8];
    const float* pw1_w = (const float*)d_in[9];
    const float* pw1_b = (const float*)d_in[10];
    const float* pw2_w = (const float*)d_in[11];
    const float* pw2_b = (const float*)d_in[12];
    const float* w_c2  = (const float*)d_in[13];
    const float* bn2_g = (const float*)d_in[15];
    const float* bn2_b = (const float*)d_in[16];
    float* out = (float*)d_out;

    const size_t n512 = (size_t)Bq * C4 * HW2;
    const size_t n128 = (size_t)Bq * Cc * HW2;
    u16* h1   = (u16*)d_ws;        // DWT out / conv2 out (disjoint lifetimes)
    u16* z2   = h1;
    u16* bufA = h1 + n512;         // conv1 raw out
    u16* bufH = bufA + n128;       // post BN1+gelu (= residual)
    u16* bufD = bufH + n128;       // dwconv raw out
    u16* bufP = bufD + n128;       // pw1 out
    u16* bufY = bufP + n128;       // pw2 out
    u16* wb   = bufY + n128;       // bf16 weights
    float* stats = (float*)(wb + 163840);
    size_t need = (n512 + 5 * n128 + 163840) * 2 + 4096 * 4;
    if (ws_size < need) return;

    float* bn1_sum = stats;
    float* bn1_sq  = stats + 128;
    float* ln_sum  = stats + 256;
    float* ln_sq   = stats + 264;
    float* bn2_sum = stats + 512;
    float* bn2_sq  = stats + 1024;
    float* wbv     = stats + 2048;
    float* wgs     = stats + 2176;

    hipMemsetAsync(stats, 0, 4096 * sizeof(float), stream);

    // 0. weights -> bf16 (+ LN-fold vectors)
    k_wconv<<<640, 256, 0, stream>>>(w_c1, pw1_w, pw2_w, w_c2, gn_g, wb);
    k_wvec<<<1, 128, 0, stream>>>(pw1_w, gn_g, gn_b, wbv, wgs);

    // 1. DWT -> h1 (pixel-major bf16)
    k_dwt<<<dim3(8, 128, 8), 256, 0, stream>>>(x, h1);

    // 2. conv1 + fused BN1 stats
    k_mfma<0, 1><<<dim3(1, 128, 8), 256, 0, stream>>>(
        h1, wb, bufA, nullptr, nullptr, nullptr, nullptr, nullptr, nullptr,
        bn1_sum, bn1_sq, 128, 512, (long)HW2 * 512, 0, (long)HW2 * 128);

    // 3. BN1 apply + gelu -> bufH
    k_bn1_gelu<<<8192, 256, 0, stream>>>(bufA, bufH, bn1_sum, bn1_sq, bn1_g, bn1_b);

    // 4. depthwise 3x3 + fused LN stats
    k_dwconv<<<dim3(8, 128, 8), 256, 0, stream>>>(bufH, bufD, dw_w, dw_b, ln_sum, ln_sq);

    // 5. pw1 on RAW bufD, LN folded into weights/affine, + gelu
    k_mfma<1, 0><<<dim3(1, 128, 8), 256, 0, stream>>>(
        bufD, wb + 65536, bufP, pw1_b, nullptr, wbv, wgs, ln_sum, ln_sq,
        nullptr, nullptr, 128, 128, (long)HW2 * 128, 0, (long)HW2 * 128);

    // 6. pw2 + bias + residual
    k_mfma<2, 0><<<dim3(1, 128, 8), 256, 0, stream>>>(
        bufP, wb + 81920, bufY, pw2_b, bufH, nullptr, nullptr, nullptr, nullptr,
        nullptr, nullptr, 128, 128, (long)HW2 * 128, 0, (long)HW2 * 128);

    // 7. conv2 (channel-major out) + fused BN2 stats
    k_mfma<0, 2><<<dim3(128, 4, 8), 256, 0, stream>>>(
        wb + 98304, bufY, z2, nullptr, nullptr, nullptr, nullptr, nullptr, nullptr,
        bn2_sum, bn2_sq, 16384, 128, 0, (long)HW2 * 128, (long)C4 * HW2);

    // 8. BN2 + gelu + IDWT -> out
    k_bn2_gelu_idwt<<<32768, 256, 0, stream>>>(z2, out, bn2_sum, bn2_sq, bn2_g, bn2_b);
}

// Round 4
// 843.264 us; speedup vs baseline: 1.1670x; 1.1670x over previous
//
#include <hip/hip_runtime.h>
#include <hip/hip_bf16.h>

typedef unsigned short u16;
typedef unsigned int u32;
typedef __attribute__((ext_vector_type(8))) short short8;
typedef __attribute__((ext_vector_type(4))) float f32x4;

#define Bq 8
#define Cc 128
#define C4 512
#define Hh 256
#define Wf 256
#define H2 128
#define W2 128
#define HW2 16384

__device__ __forceinline__ float gelu_f(float x) {
    return 0.5f * x * (1.0f + erff(x * 0.70710678118654752f));
}
__device__ __forceinline__ float bf2f(u16 u) {
    union { float f; u32 i; } v; v.i = ((u32)u) << 16; return v.f;
}
__device__ __forceinline__ u16 f2bf(float f) {
    union { float f; u32 i; } v; v.f = f;
    u32 r = v.i + 0x7FFFu + ((v.i >> 16) & 1u);
    return (u16)(r >> 16);
}

// ---------------- weights f32 -> bf16 (pw1 pre-scaled by gn_g) ----------------
__global__ __launch_bounds__(256) void k_wconv(const float* __restrict__ w_c1,
                                               const float* __restrict__ pw1,
                                               const float* __restrict__ pw2,
                                               const float* __restrict__ w_c2,
                                               const float* __restrict__ gn_g,
                                               u16* __restrict__ wb) {
    int i = blockIdx.x * 256 + threadIdx.x;   // 0..163839
    float v;
    if (i < 65536) v = w_c1[i];
    else if (i < 81920) v = pw1[i - 65536] * gn_g[(i - 65536) & 127];
    else if (i < 98304) v = pw2[i - 81920];
    else v = w_c2[i - 98304];
    wb[i] = f2bf(v);
}

// ---------------- LN-fold vectors: wgs[o]=sum_c w*g, wbv[o]=sum_c w*b --------
__global__ __launch_bounds__(128) void k_wvec(const float* __restrict__ pw1,
                                              const float* __restrict__ gg,
                                              const float* __restrict__ gb,
                                              float* __restrict__ wbv,
                                              float* __restrict__ wgs) {
    int o = threadIdx.x;
    float a = 0.f, bv = 0.f;
    for (int c = 0; c < 128; ++c) {
        float w = pw1[o * 128 + c];
        a += w * gg[c];
        bv += w * gb[c];
    }
    wgs[o] = a;
    wbv[o] = bv;
}

// ---------------- DWT: x NCHW f32 -> h1 pixel-major bf16 [b][pix][512] --------
__global__ __launch_bounds__(256) void k_dwt(const float* __restrict__ x,
                                             u16* __restrict__ h1) {
    __shared__ float lin[2 * 4224];
    __shared__ __align__(16) u16 obuf[16 * 512];
    const int t = threadIdx.x;
    const int b = blockIdx.z, oi = blockIdx.y, jt = blockIdx.x;
    {
        int c = t & 127, h = t >> 7;
        const float* xp = x + (((long)(b * Cc + c)) * Hh + (2 * oi + h)) * Wf + jt * 32;
        float* lp = lin + h * 4224 + c * 33;
#pragma unroll
        for (int q = 0; q < 8; ++q) {
            float4 v = *(const float4*)(xp + q * 4);
            lp[q * 4 + 0] = v.x; lp[q * 4 + 1] = v.y;
            lp[q * 4 + 2] = v.z; lp[q * 4 + 3] = v.w;
        }
    }
    __syncthreads();
    {
        int c = t & 127, pg = t >> 7;
        const float* l0 = lin + c * 33;
        const float* l1 = lin + 4224 + c * 33;
#pragma unroll
        for (int u = 0; u < 8; ++u) {
            int p = pg * 8 + u;
            float x00 = l0[2 * p], x01 = l0[2 * p + 1];
            float x10 = l1[2 * p], x11 = l1[2 * p + 1];
            obuf[p * 512 + 0 * 128 + c] = f2bf((x00 + x01 + x10 + x11) * 0.5f);
            obuf[p * 512 + 1 * 128 + c] = f2bf((x00 + x01 - x10 - x11) * 0.5f);
            obuf[p * 512 + 2 * 128 + c] = f2bf((x00 - x01 + x10 - x11) * 0.5f);
            obuf[p * 512 + 3 * 128 + c] = f2bf((x00 - x01 - x10 + x11) * 0.5f);
        }
    }
    __syncthreads();
    {
        int p = t >> 4, seg = t & 15;
        long opix = (long)b * HW2 + (long)oi * W2 + jt * 16 + p;
        const uint4* src = (const uint4*)(obuf + p * 512 + seg * 32);
        uint4* dst = (uint4*)(h1 + opix * 512 + seg * 32);
        dst[0] = src[0]; dst[1] = src[1]; dst[2] = src[2]; dst[3] = src[3];
    }
}

// ---------------- bf16 MFMA NT-GEMM with fused stats + coalesced epilogue -----
// C[M][N] = A[M][K] * B[N][K]^T.
// EPI: 0 raw bf16 store; 1 LN-folded affine + gelu (pw1); 2 +bias +residual (pw2)
// STATS: 0 none; 1 per-col sum/sq (conv1); 2 per-row (conv2)
// Stats atomics are PADDED: value i lives at statX[i*16] (own cache line).
// For EPI==1, lnS/lnQ are 64 padded partial slots per batch: lnS[(b*64+s)*16].
template <int EPI, int STATS>
__global__ __launch_bounds__(256) void k_mfma(const u16* __restrict__ A,
                                              const u16* __restrict__ Bw,
                                              u16* __restrict__ C,
                                              const float* __restrict__ bias,
                                              const u16* __restrict__ res,
                                              const float* __restrict__ wbv,
                                              const float* __restrict__ wgs,
                                              const float* __restrict__ lnS,
                                              const float* __restrict__ lnQ,
                                              float* __restrict__ statS,
                                              float* __restrict__ statQ,
                                              int N, int K,
                                              long aBs, long bBs, long cBs) {
    __shared__ __align__(16) u16 lds[16384];   // staging (2x8K), then C bounce
    __shared__ float sblk[128], qblk[128];
    __shared__ float lnred[2];
    const int t = threadIdx.x;
    const int lane = t & 63, w = t >> 6, wr = w >> 1, wc = w & 1;
    const int b = blockIdx.z;
    const int m0 = blockIdx.y * 128, n0 = blockIdx.x * 128;
    const u16* Ab = A + (long)b * aBs + (long)m0 * K;
    const u16* Bb = Bw + (long)b * bBs + (long)n0 * K;

    if (EPI == 1) {
        if (t < 64) {   // reduce 64 padded LN partial slots
            float s = lnS[((long)b * 64 + t) * 16];
            float q = lnQ[((long)b * 64 + t) * 16];
#pragma unroll
            for (int off = 32; off; off >>= 1) {
                s += __shfl_down(s, off);
                q += __shfl_down(q, off);
            }
            if (t == 0) { lnred[0] = s; lnred[1] = q; }
        }
        __syncthreads();
    }
    if (t < 128) {
        if (STATS) { sblk[t] = 0.f; qblk[t] = 0.f; }
        if (EPI == 1) {
            const float invN = 1.0f / 2097152.0f;
            float mu = lnred[0] * invN;
            float var = lnred[1] * invN - mu * mu;
            float rs2 = rsqrtf(var + 1e-5f);
            sblk[t] = bias[t] + wbv[t] - mu * rs2 * wgs[t];
        }
        if (EPI == 2) sblk[t] = bias[t];
    }

    uint4 ra[4], rb[4];
#define GLOAD(dst, base, k0)                                                     \
    {                                                                            \
        _Pragma("unroll")                                                        \
        for (int i = 0; i < 4; ++i) {                                            \
            int s = i * 256 + t;                                                 \
            dst[i] = *(const uint4*)(base + (long)(s >> 3) * K + (k0) + (s & 7) * 8); \
        }                                                                        \
    }
#define LWRITE(ofs, src)                                                         \
    {                                                                            \
        _Pragma("unroll")                                                        \
        for (int i = 0; i < 4; ++i) {                                            \
            int s = i * 256 + t;                                                 \
            int row_ = s >> 3, ch_ = s & 7;                                      \
            *(uint4*)((char*)lds + (ofs) + row_ * 128 + 16 * (ch_ ^ (row_ & 7))) = src[i]; \
        }                                                                        \
    }

    f32x4 acc[4][4];
#pragma unroll
    for (int i = 0; i < 4; ++i)
#pragma unroll
        for (int j = 0; j < 4; ++j) acc[i][j] = (f32x4){0.f, 0.f, 0.f, 0.f};

    GLOAD(ra, Ab, 0)
    GLOAD(rb, Bb, 0)
    const int r15 = lane & 15, kq = lane >> 4;
    for (int k0 = 0; k0 < K; k0 += 64) {
        __syncthreads();
        LWRITE(0, ra)
        LWRITE(16384, rb)
        __syncthreads();
        if (k0 + 64 < K) { GLOAD(ra, Ab, k0 + 64) GLOAD(rb, Bb, k0 + 64) }
#pragma unroll
        for (int ks = 0; ks < 2; ++ks) {
            short8 af[4], bfv[4];
            const int ch = ks * 4 + kq;
#pragma unroll
            for (int mi = 0; mi < 4; ++mi) {
                int row = wr * 64 + mi * 16 + r15;
                af[mi] = *(const short8*)((const char*)lds + row * 128 + 16 * (ch ^ (row & 7)));
            }
#pragma unroll
            for (int ni = 0; ni < 4; ++ni) {
                int row = wc * 64 + ni * 16 + r15;
                bfv[ni] = *(const short8*)((const char*)lds + 16384 + row * 128 + 16 * (ch ^ (row & 7)));
            }
#pragma unroll
            for (int mi = 0; mi < 4; ++mi)
#pragma unroll
                for (int ni = 0; ni < 4; ++ni)
                    acc[mi][ni] = __builtin_amdgcn_mfma_f32_16x16x32_bf16(
                        af[mi], bfv[ni], acc[mi][ni], 0, 0, 0);
        }
    }
    __syncthreads();   // staging reads done; lds reusable as C bounce

    // --- bounce raw acc (bf16) into lds: [row][col ^ ((row&7)<<3)] ---
#pragma unroll
    for (int mi = 0; mi < 4; ++mi)
#pragma unroll
        for (int ni = 0; ni < 4; ++ni)
#pragma unroll
            for (int r = 0; r < 4; ++r) {
                int row = wr * 64 + mi * 16 + kq * 4 + r;
                int col = wc * 64 + ni * 16 + r15;
                lds[row * 128 + (col ^ ((row & 7) << 3))] = f2bf(acc[mi][ni][r]);
            }

    // --- fused stats from f32 acc (block-level into LDS) ---
    if (STATS == 1) {   // per-col (cols = channels), reduce over rows
#pragma unroll
        for (int ni = 0; ni < 4; ++ni) {
            float s = 0.f, q2 = 0.f;
#pragma unroll
            for (int mi = 0; mi < 4; ++mi)
#pragma unroll
                for (int r = 0; r < 4; ++r) {
                    float v = acc[mi][ni][r];
                    s += v; q2 += v * v;
                }
            s += __shfl_down(s, 32); s += __shfl_down(s, 16);
            q2 += __shfl_down(q2, 32); q2 += __shfl_down(q2, 16);
            if (lane < 16) {
                int col = wc * 64 + ni * 16 + r15;
                atomicAdd(&sblk[col], s);
                atomicAdd(&qblk[col], q2);
            }
        }
    }
    if (STATS == 2) {   // per-row (rows = channels), reduce over cols
#pragma unroll
        for (int mi = 0; mi < 4; ++mi)
#pragma unroll
            for (int r = 0; r < 4; ++r) {
                float s = 0.f, q2 = 0.f;
#pragma unroll
                for (int ni = 0; ni < 4; ++ni) {
                    float v = acc[mi][ni][r];
                    s += v; q2 += v * v;
                }
                s += __shfl_down(s, 8); s += __shfl_down(s, 4);
                s += __shfl_down(s, 2); s += __shfl_down(s, 1);
                q2 += __shfl_down(q2, 8); q2 += __shfl_down(q2, 4);
                q2 += __shfl_down(q2, 2); q2 += __shfl_down(q2, 1);
                if (r15 == 0) {
                    int row = wr * 64 + mi * 16 + kq * 4 + r;
                    atomicAdd(&sblk[row], s);
                    atomicAdd(&qblk[row], q2);
                }
            }
    }
    __syncthreads();   // C tile + block stats complete

    // --- coalesced read-back + epilogue transform + uint4 stores ---
    u16* Cb = C + (long)b * cBs;
    {
        int row = t >> 1, half = (t & 1) * 64;
        int sx = (row & 7) << 3;
        long gbase = (long)(m0 + row) * N + n0;
        float rs = 1.f;
        if (EPI == 1) {
            const float invN = 1.0f / 2097152.0f;
            float mu = lnred[0] * invN;
            float var = lnred[1] * invN - mu * mu;
            rs = rsqrtf(var + 1e-5f);
        }
#pragma unroll
        for (int q = 0; q < 8; ++q) {
            int c = half + q * 8;
            uint4 raw = *(const uint4*)(lds + row * 128 + (c ^ sx));
            if (EPI == 0) {
                *(uint4*)(Cb + gbase + c) = raw;
            } else {
                u16* pv = (u16*)&raw;
                uint4 rr;
                if (EPI == 2) rr = *(const uint4*)(res + (long)b * cBs + gbase + c);
                const u16* rv = (const u16*)&rr;
#pragma unroll
                for (int u = 0; u < 8; ++u) {
                    float v = bf2f(pv[u]);
                    if (EPI == 1) v = gelu_f(rs * v + sblk[c + u]);
                    if (EPI == 2) v = v + sblk[c + u] + bf2f(rv[u]);
                    pv[u] = f2bf(v);
                }
                *(uint4*)(Cb + gbase + c) = raw;
            }
        }
    }
    // --- padded global atomics: one cache line per stat value ---
    if (STATS && t < 128) {
        int base = (STATS == 1) ? n0 : m0;
        atomicAdd(statS + (long)(base + t) * 16, sblk[t]);
        atomicAdd(statQ + (long)(base + t) * 16, qblk[t]);
    }
#undef GLOAD
#undef LWRITE
}

// ---------------- BN1 apply + gelu: bufA -> bufH (padded stats) ----------------
__global__ __launch_bounds__(256) void k_bn1_gelu(const u16* __restrict__ in,
                                                  u16* __restrict__ out,
                                                  const float* __restrict__ sum,
                                                  const float* __restrict__ sq,
                                                  const float* __restrict__ g,
                                                  const float* __restrict__ bb) {
    long e = ((long)blockIdx.x * 256 + threadIdx.x) * 8;
    int c0 = (int)(e & 127);
    uint4 raw = *(const uint4*)(in + e);
    u16* pv = (u16*)&raw;
    const float invN = 1.0f / 131072.0f;
#pragma unroll
    for (int u = 0; u < 8; ++u) {
        int c = c0 + u;
        float mu = sum[(long)c * 16] * invN;
        float var = sq[(long)c * 16] * invN - mu * mu;
        float rscale = rsqrtf(var + 1e-5f);
        float sc = rscale * g[c], sh = bb[c] - mu * sc;
        pv[u] = f2bf(gelu_f(bf2f(pv[u]) * sc + sh));
    }
    *(uint4*)(out + e) = raw;
}

// ---------------- depthwise 3x3 NHWC bf16 + fused LN stats (64 slots/batch) ---
__global__ __launch_bounds__(256) void k_dwconv(const u16* __restrict__ x,
                                                u16* __restrict__ y,
                                                const float* __restrict__ w,
                                                const float* __restrict__ bias,
                                                float* __restrict__ lnS,
                                                float* __restrict__ lnQ) {
    __shared__ float wl2[1152];   // [tap][u][cg] -> conflict-free lane->bank map
    const int t = threadIdx.x;
    for (int idx = t; idx < 1152; idx += 256) {
        int c = idx / 9, tap = idx - c * 9;
        wl2[tap * 128 + (c & 7) * 16 + (c >> 3)] = w[idx];
    }
    __syncthreads();
    const int cg = t & 15, jj = t >> 4;
    const int j = blockIdx.x * 16 + jj, i = blockIdx.y, b = blockIdx.z;
    const u16* xb = x + (long)b * HW2 * 128 + cg * 8;
    // prefetch all 9 neighborhood uint4 loads
    uint4 raw[3][3];
    const uint4 z4 = make_uint4(0u, 0u, 0u, 0u);
#pragma unroll
    for (int r = 0; r < 3; ++r) {
        int row = i - 1 + r;
#pragma unroll
        for (int q = 0; q < 3; ++q) {
            int col = j - 1 + q;
            bool ok = (row >= 0) & (row < H2) & (col >= 0) & (col < W2);
            raw[r][q] = ok ? *(const uint4*)(xb + ((long)row * W2 + col) * 128) : z4;
        }
    }
    float acc[8];
#pragma unroll
    for (int u = 0; u < 8; ++u) acc[u] = bias[cg * 8 + u];
#pragma unroll
    for (int r = 0; r < 3; ++r)
#pragma unroll
        for (int q = 0; q < 3; ++q) {
            const u16* pv = (const u16*)&raw[r][q];
            const int tap = r * 3 + q;
#pragma unroll
            for (int u = 0; u < 8; ++u)
                acc[u] = fmaf(bf2f(pv[u]), wl2[tap * 128 + u * 16 + cg], acc[u]);
        }
    uint4 outv; u16* ov = (u16*)&outv;
    float s = 0.f, q2 = 0.f;
#pragma unroll
    for (int u = 0; u < 8; ++u) {
        ov[u] = f2bf(acc[u]);
        s += acc[u]; q2 += acc[u] * acc[u];
    }
    *(uint4*)(y + ((long)b * HW2 + (long)i * W2 + j) * 128 + cg * 8) = outv;
#pragma unroll
    for (int off = 32; off; off >>= 1) {
        s += __shfl_down(s, off);
        q2 += __shfl_down(q2, off);
    }
    __shared__ float r1[4], r2[4];
    if ((t & 63) == 0) { r1[t >> 6] = s; r2[t >> 6] = q2; }
    __syncthreads();
    if (t == 0) {
        int slot = (blockIdx.y * 8 + blockIdx.x) & 63;
        atomicAdd(lnS + ((long)b * 64 + slot) * 16, r1[0] + r1[1] + r1[2] + r1[3]);
        atomicAdd(lnQ + ((long)b * 64 + slot) * 16, r2[0] + r2[1] + r2[2] + r2[3]);
    }
}

// ---------------- BN2 + GELU + IDWT: z channel-major bf16 -> out f32 NCHW -----
__global__ __launch_bounds__(256) void k_bn2_gelu_idwt(const u16* __restrict__ z,
                                                       float* __restrict__ out,
                                                       const float* __restrict__ sum,
                                                       const float* __restrict__ sq,
                                                       const float* __restrict__ g,
                                                       const float* __restrict__ bb) {
    int tid = blockIdx.x * 256 + threadIdx.x;
    int j2 = tid & 63;
    int i  = (tid >> 6) & 127;
    int c  = (tid >> 13) & 127;
    int b  = tid >> 20;
    const float invN = 1.0f / 131072.0f;
    long qs = (long)Cc * HW2;
    long base = (((long)b * C4 + c) * H2 + i) * W2 + 2 * j2;
    float sb[4][2];
#pragma unroll
    for (int q = 0; q < 4; ++q) {
        int ch = q * 128 + c;
        float mu = sum[(long)ch * 16] * invN;
        float var = sq[(long)ch * 16] * invN - mu * mu;
        float rscale = rsqrtf(var + 1e-5f);
        float sc = rscale * g[ch], sh = bb[ch] - mu * sc;
        u32 raw = *(const u32*)(z + base + (long)q * qs);
        sb[q][0] = gelu_f(bf2f((u16)(raw & 0xFFFFu)) * sc + sh);
        sb[q][1] = gelu_f(bf2f((u16)(raw >> 16)) * sc + sh);
    }
    float4 top, bot;
    float* tp = &top.x;
    float* bp = &bot.x;
#pragma unroll
    for (int px = 0; px < 2; ++px) {
        float ll = sb[0][px], lh = sb[1][px], hl = sb[2][px], hh = sb[3][px];
        tp[px * 2 + 0] = (ll + lh + hl + hh) * 0.5f;
        tp[px * 2 + 1] = (ll + lh - hl - hh) * 0.5f;
        bp[px * 2 + 0] = (ll - lh + hl - hh) * 0.5f;
        bp[px * 2 + 1] = (ll - lh - hl + hh) * 0.5f;
    }
    float* optr = out + ((long)(b * Cc + c) * Hh + 2 * i) * Wf + 4 * j2;
    *(float4*)optr = top;
    *(float4*)(optr + Wf) = bot;
}

extern "C" void kernel_launch(void* const* d_in, const int* in_sizes, int n_in,
                              void* d_out, int out_size, void* d_ws, size_t ws_size,
                              hipStream_t stream) {
    const float* x     = (const float*)d_in[0];
    const float* w_c1  = (const float*)d_in[1];
    const float* bn1_g = (const float*)d_in[3];
    const float* bn1_b = (const float*)d_in[4];
    const float* dw_w  = (const float*)d_in[5];
    const float* dw_b  = (const float*)d_in[6];
    const float* gn_g  = (const float*)d_in[7];
    const float* gn_b  = (const float*)d_in[8];
    const float* pw1_w = (const float*)d_in[9];
    const float* pw1_b = (const float*)d_in[10];
    const float* pw2_w = (const float*)d_in[11];
    const float* pw2_b = (const float*)d_in[12];
    const float* w_c2  = (const float*)d_in[13];
    const float* bn2_g = (const float*)d_in[15];
    const float* bn2_b = (const float*)d_in[16];
    float* out = (float*)d_out;

    const size_t n512 = (size_t)Bq * C4 * HW2;
    const size_t n128 = (size_t)Bq * Cc * HW2;
    u16* h1   = (u16*)d_ws;        // DWT out / conv2 out (disjoint lifetimes)
    u16* z2   = h1;
    u16* bufA = h1 + n512;         // conv1 raw out
    u16* bufH = bufA + n128;       // post BN1+gelu (= residual)
    u16* bufD = bufH + n128;       // dwconv raw out
    u16* bufP = bufD + n128;       // pw1 out
    u16* bufY = bufP + n128;       // pw2 out
    u16* wb   = bufY + n128;       // bf16 weights
    float* stats = (float*)(wb + 163840);
    size_t need = (n512 + 5 * n128 + 163840) * 2 + 40960 * 4;
    if (ws_size < need) return;

    // padded stats layout (floats), each logical value on its own 64-B line:
    float* bn1_sum = stats;            // 128 vals * 16
    float* bn1_sq  = stats + 2048;     // 128 vals * 16
    float* ln_sum  = stats + 4096;     // 8 batches * 64 slots * 16
    float* ln_sq   = stats + 12288;
    float* bn2_sum = stats + 20480;    // 512 vals * 16
    float* bn2_sq  = stats + 28672;
    float* wbv     = stats + 36864;    // 128 (dense)
    float* wgs     = stats + 36992;    // 128 (dense)

    hipMemsetAsync(stats, 0, 36864 * sizeof(float), stream);

    // 0. weights -> bf16 (+ LN-fold vectors)
    k_wconv<<<640, 256, 0, stream>>>(w_c1, pw1_w, pw2_w, w_c2, gn_g, wb);
    k_wvec<<<1, 128, 0, stream>>>(pw1_w, gn_g, gn_b, wbv, wgs);

    // 1. DWT -> h1 (pixel-major bf16)
    k_dwt<<<dim3(8, 128, 8), 256, 0, stream>>>(x, h1);

    // 2. conv1 + fused BN1 stats (padded atomics)
    k_mfma<0, 1><<<dim3(1, 128, 8), 256, 0, stream>>>(
        h1, wb, bufA, nullptr, nullptr, nullptr, nullptr, nullptr, nullptr,
        bn1_sum, bn1_sq, 128, 512, (long)HW2 * 512, 0, (long)HW2 * 128);

    // 3. BN1 apply + gelu -> bufH
    k_bn1_gelu<<<8192, 256, 0, stream>>>(bufA, bufH, bn1_sum, bn1_sq, bn1_g, bn1_b);

    // 4. depthwise 3x3 + fused LN stats (64 padded slots/batch)
    k_dwconv<<<dim3(8, 128, 8), 256, 0, stream>>>(bufH, bufD, dw_w, dw_b, ln_sum, ln_sq);

    // 5. pw1 on RAW bufD, LN folded into weights/affine, + gelu
    k_mfma<1, 0><<<dim3(1, 128, 8), 256, 0, stream>>>(
        bufD, wb + 65536, bufP, pw1_b, nullptr, wbv, wgs, ln_sum, ln_sq,
        nullptr, nullptr, 128, 128, (long)HW2 * 128, 0, (long)HW2 * 128);

    // 6. pw2 + bias + residual
    k_mfma<2, 0><<<dim3(1, 128, 8), 256, 0, stream>>>(
        bufP, wb + 81920, bufY, pw2_b, bufH, nullptr, nullptr, nullptr, nullptr,
        nullptr, nullptr, 128, 128, (long)HW2 * 128, 0, (long)HW2 * 128);

    // 7. conv2 (channel-major out) + fused BN2 stats (padded atomics)
    k_mfma<0, 2><<<dim3(128, 4, 8), 256, 0, stream>>>(
        wb + 98304, bufY, z2, nullptr, nullptr, nullptr, nullptr, nullptr, nullptr,
        bn2_sum, bn2_sq, 16384, 128, 0, (long)HW2 * 128, (long)C4 * HW2);

    // 8. BN2 + gelu + IDWT -> out
    k_bn2_gelu_idwt<<<32768, 256, 0, stream>>>(z2, out, bn2_sum, bn2_sq, bn2_g, bn2_b);
}